// Round 1
// 328.769 us; speedup vs baseline: 1.0828x; 1.0828x over previous
//
#include <hip/hip_runtime.h>
#include <hip/hip_bf16.h>
#include <stdint.h>

#define Tdim 4096
#define Ndim 4096
#define Kdim 4096
#define K2   4160   // 4096 + 32 (low-rank concat) + 32 (zero pad to multiple of 64)
#define NSPLIT 16   // K-splits for the low-rank partial GEMM
#define NT   130    // K2 / 32 K-steps for the main GEMM

using f32x4  = __attribute__((ext_vector_type(4))) float;
using bf16x8 = __attribute__((ext_vector_type(8))) short;

// round-to-nearest-even f32 -> bf16 bits
__device__ inline ushort f2bf(float f) {
  union { float f; unsigned u; } v; v.f = f;
  unsigned lsb = (v.u >> 16) & 1u;
  v.u += 0x7fffu + lsb;
  return (ushort)(v.u >> 16);
}

__device__ inline unsigned pack2(float a, float b) {
  return (unsigned)f2bf(a) | ((unsigned)f2bf(b) << 16);
}

__device__ inline float qd(float v, float s) {   // quantize-dequantize
  return fminf(fmaxf(rintf(v / s), -8.f), 7.f) * s;
}

__device__ inline void async16(const void* g, void* l) {
  __builtin_amdgcn_global_load_lds(
      (const __attribute__((address_space(1))) unsigned int*)g,
      (__attribute__((address_space(3))) unsigned int*)l, 16, 0, 0);
}

// ---------------- K0: pdT[n][k] = bf16(pd[k][n])  (32 x 4096) ---------------
__global__ __launch_bounds__(256) void prep_pdT_kernel(
    const float* __restrict__ pd, ushort* __restrict__ pdT) {
  const int idx = blockIdx.x * 256 + threadIdx.x;   // 32*4096 threads
  const int n = idx >> 12;
  const int k = idx & 4095;
  pdT[(size_t)n * Kdim + k] = f2bf(pd[(size_t)k * 32 + n]);
}

// ========== K1: fused activation quant-dequant + low-rank partial GEMM ======
// grid (32 token-tiles, 16 k-splits); block covers 128 tokens x 256 k.
// Writes A[token][0..4095] (bf16 qdq values) and partials[split][T][32].
__global__ __launch_bounds__(256) void prep_a_kernel(
    const float* __restrict__ x, const float* __restrict__ smooth,
    const ushort* __restrict__ pdT, ushort* __restrict__ A,
    float* __restrict__ partials) {
  __shared__ __attribute__((aligned(16))) ushort sXS[128 * 136];  // xs (bf16) for MFMA
  __shared__ __attribute__((aligned(16))) ushort sQ[128 * 136];   // qdq(xs) for A
  const int tid  = threadIdx.x;
  const int lane = tid & 63;
  const int wave = tid >> 6;
  const int fr  = lane & 15;
  const int fkq = lane >> 4;
  const int fk  = fkq * 8;
  const int tok0 = blockIdx.x * 128;
  const int kc0  = blockIdx.y * 256;
  const int r = tid >> 1;          // token row 0..127
  const int g = tid & 1;           // which 64-group of the 128-k chunk
  const int srow2 = tid >> 2;      // A-store: row 0..63 (+64)
  const int scol2 = (tid & 3) * 8; // A-store: col

  f32x4 acc[2][2] = {};

  for (int c = 0; c < 2; ++c) {
    const int kbase = kc0 + c * 128;
    const int kcol  = g * 64;
    const float4* xp = (const float4*)&x[(size_t)(tok0 + r) * Kdim + kbase + kcol];
    const float4* sp = (const float4*)&smooth[kbase + kcol];
    float4 v[16];
#pragma unroll
    for (int q = 0; q < 16; ++q) {
      float4 xv = xp[q], sm = sp[q];
      v[q].x = xv.x * sm.x; v[q].y = xv.y * sm.y;
      v[q].z = xv.z * sm.z; v[q].w = xv.w * sm.w;
    }
    float a = 0.f;
#pragma unroll
    for (int q = 0; q < 16; ++q)
      a = fmaxf(a, fmaxf(fmaxf(fabsf(v[q].x), fabsf(v[q].y)),
                         fmaxf(fabsf(v[q].z), fabsf(v[q].w))));
    const float s = fmaxf(a / 7.0f, 1e-8f);   // exact div: must match np
#pragma unroll
    for (int q2 = 0; q2 < 8; ++q2) {
      const float4 v0 = v[2 * q2], v1 = v[2 * q2 + 1];
      uint4 wx, wq;
      wx.x = pack2(v0.x, v0.y);           wx.y = pack2(v0.z, v0.w);
      wx.z = pack2(v1.x, v1.y);           wx.w = pack2(v1.z, v1.w);
      wq.x = pack2(qd(v0.x, s), qd(v0.y, s)); wq.y = pack2(qd(v0.z, s), qd(v0.w, s));
      wq.z = pack2(qd(v1.x, s), qd(v1.y, s)); wq.w = pack2(qd(v1.z, s), qd(v1.w, s));
      *(uint4*)&sXS[r * 136 + kcol + q2 * 8] = wx;
      *(uint4*)&sQ [r * 136 + kcol + q2 * 8] = wq;
    }
    __syncthreads();

    // low-rank MFMA: t_partial += xs_tile @ pdT_tile (B fragments via vec loads)
#pragma unroll
    for (int kk = 0; kk < 4; ++kk) {
      const int kglob = kbase + kk * 32 + fk;
      bf16x8 af0 = *(const bf16x8*)&sXS[(wave * 32 + fr) * 136 + kk * 32 + fk];
      bf16x8 af1 = *(const bf16x8*)&sXS[(wave * 32 + 16 + fr) * 136 + kk * 32 + fk];
      bf16x8 b0 = *(const bf16x8*)&pdT[(size_t)fr * Kdim + kglob];
      bf16x8 b1 = *(const bf16x8*)&pdT[(size_t)(16 + fr) * Kdim + kglob];
      acc[0][0] = __builtin_amdgcn_mfma_f32_16x16x32_bf16(af0, b0, acc[0][0], 0, 0, 0);
      acc[0][1] = __builtin_amdgcn_mfma_f32_16x16x32_bf16(af0, b1, acc[0][1], 0, 0, 0);
      acc[1][0] = __builtin_amdgcn_mfma_f32_16x16x32_bf16(af1, b0, acc[1][0], 0, 0, 0);
      acc[1][1] = __builtin_amdgcn_mfma_f32_16x16x32_bf16(af1, b1, acc[1][1], 0, 0, 0);
    }

    // coalesced A store from sQ
#pragma unroll
    for (int h = 0; h < 2; ++h) {
      const int rr = srow2 + h * 64;
#pragma unroll
      for (int u = 0; u < 4; ++u)
        *(uint4*)&A[(size_t)(tok0 + rr) * K2 + kbase + scol2 + u * 32] =
            *(const uint4*)&sQ[rr * 136 + scol2 + u * 32];
    }
    __syncthreads();
  }

  float* P = partials + (size_t)blockIdx.y * Tdim * 32;
#pragma unroll
  for (int i = 0; i < 2; ++i) {
    const int row0 = tok0 + wave * 32 + i * 16 + fkq * 4;
#pragma unroll
    for (int j = 0; j < 2; ++j) {
      const int col = j * 16 + fr;
#pragma unroll
      for (int rr = 0; rr < 4; ++rr)
        P[(size_t)(row0 + rr) * 32 + col] = acc[i][j][rr];
    }
  }
}

// ====== K2: weight dequant (bid<8192) | A-tail reduce (8192..9215) | B-tail ==
__global__ __launch_bounds__(256) void wprep_kernel(
    const int* __restrict__ qw, const float* __restrict__ wsc,
    const float* __restrict__ partials, const float* __restrict__ pu,
    ushort* __restrict__ A, ushort* __restrict__ B) {
  const int bid = blockIdx.x;
  if (bid < 8192) {
    // dequantize int4 weights -> B' bf16, 8 elems/thread
    const size_t idx = ((size_t)bid * 256 + threadIdx.x) * 8;
    const int n = (int)(idx >> 12);
    const int k = (int)(idx & 4095);
    const float s = wsc[n * 64 + (k >> 6)];
    const int4 q0 = *(const int4*)(qw + idx);
    const int4 q1 = *(const int4*)(qw + idx + 4);
    uint4 o;
    o.x = pack2((float)q0.x * s, (float)q0.y * s);
    o.y = pack2((float)q0.z * s, (float)q0.w * s);
    o.z = pack2((float)q1.x * s, (float)q1.y * s);
    o.w = pack2((float)q1.z * s, (float)q1.w * s);
    *(uint4*)(B + (size_t)n * K2 + k) = o;
  } else if (bid < 8192 + 1024) {
    // reduce K-split partials -> bf16 into A tail cols [4096..4160)
    const int idx = (bid - 8192) * 256 + threadIdx.x;   // T*64 threads
    const int token = idx >> 6, c = idx & 63;
    ushort v = 0;
    if (c < 32) {
      float s = 0.f;
#pragma unroll
      for (int p = 0; p < NSPLIT; ++p)
        s += partials[(size_t)p * Tdim * 32 + (size_t)token * 32 + c];
      v = f2bf(s);
    }
    A[(size_t)token * K2 + Kdim + c] = v;
  } else {
    // B tail cols = [bf16(pu^T) | zeros]
    const int idx = (bid - 9216) * 256 + threadIdx.x;   // N*64 threads
    const int n = idx >> 6, c = idx & 63;
    ushort v = 0;
    if (c < 32) v = f2bf(pu[(size_t)c * Ndim + n]);     // proj_up is [32, N]
    B[(size_t)n * K2 + Kdim + c] = v;
  }
}

// ========== K3: C = A' @ B'^T + bias ========================================
// 256x256 tile, 8 waves (2M x 4N), BK=32 K-steps, ring-3 LDS slots per operand
// (96 KB total). Staging runs TWO K-steps ahead of compute (provably race-free:
// the slot being filled was fully consumed one whole group before the issue),
// raw s_barriers with counted s_waitcnt vmcnt(4) once per K-step -> 8 loads
// stay in flight across barriers (T3+T4). setprio around MFMA bursts (T5).
// LDS chunk-XOR swizzle (c' = c ^ ((row>>1)&3)) applied via pre-swizzled
// global source so global_load_lds dest stays linear (rule #21); ds_read side
// un-swizzles with the same involution -> conflict-free ds_read_b128.
__global__ __launch_bounds__(512, 2) void gemm_kernel(
    const ushort* __restrict__ A, const ushort* __restrict__ B,
    const float* __restrict__ bias, float* __restrict__ C) {
  __shared__ __attribute__((aligned(16))) ushort sA[3 * 8192];  // 48 KB
  __shared__ __attribute__((aligned(16))) ushort sB[3 * 8192];  // 48 KB
  const int tid  = threadIdx.x;
  const int lane = tid & 63;
  const int wave = tid >> 6;
  const int wm = wave >> 2;            // 0..1: which 128-row half
  const int wn = wave & 3;             // 0..3: which 64-col quarter
  const int fr  = lane & 15;
  const int fkq = lane >> 4;           // 0..3: k-chunk of the fragment
  const int fchunk = (fkq ^ ((fr >> 1) & 3)) * 8;   // un-swizzled read chunk

  // XCD-chunked block swizzle: XCD x (= bid & 7) owns a 4x8 rectangle of the
  // 16x16 block grid (256 blocks, nwg % 8 == 0 -> bijective).
  const int bid  = blockIdx.x;
  const int xcd  = bid & 7;
  const int i0   = bid >> 3;           // 0..31 within XCD
  const int brow = (xcd >> 1) * 4 + (i0 >> 3);
  const int bcol = (xcd & 1) * 8 + (i0 & 7);
  const size_t arow0 = (size_t)brow * 256;
  const size_t brow0 = (size_t)bcol * 256;

  // staging: thread fills LDS rows tid>>2 and tid>>2+128, chunk tid&3;
  // source column chunk is pre-swizzled so LDS dest is linear.
  const int srow = tid >> 2;                            // 0..127
  const int swz  = ((tid & 3) ^ ((tid >> 3) & 3)) * 8;  // source chunk
  const ushort* gA = A + (arow0 + srow) * K2 + swz;
  const ushort* gB = B + (brow0 + srow) * K2 + swz;

  const int rbase = wm * 128;    // wave's row base within the 256-row tile
  const int cbase = wn * 64;     // wave's col base within the 256-col tile

  f32x4 acc[8][4] = {};

#define MF(i, j, a, b) \
  acc[i][j] = __builtin_amdgcn_mfma_f32_16x16x32_bf16(a, b, acc[i][j], 0, 0, 0)
#define STAGE_A(st, so) \
  { async16(gA + (size_t)(st) * 32,                    &sA[(so) + tid * 8]);         \
    async16(gA + (size_t)(st) * 32 + (size_t)128 * K2, &sA[(so) + (tid + 512) * 8]); }
#define STAGE_B(st, so) \
  { async16(gB + (size_t)(st) * 32,                    &sB[(so) + tid * 8]);         \
    async16(gB + (size_t)(st) * 32 + (size_t)128 * K2, &sB[(so) + (tid + 512) * 8]); }
#define FENCE() asm volatile("" ::: "memory")
#define BARRIER() { FENCE(); __builtin_amdgcn_s_barrier(); FENCE(); }

  // ---- prologue: stage K-steps 0 and 1 (slots 0,1); wait for step 0 ----
  STAGE_A(0, 0); STAGE_B(0, 0);
  STAGE_A(1, 8192); STAGE_B(1, 8192);
  asm volatile("s_waitcnt vmcnt(4)" ::: "memory");   // step 0 landed
  BARRIER();

  for (int s = 0; s < NT; ++s) {
    const int sl  = (s % 3) * 8192;
    const int sn  = s + 2;
    const int sln = (sn % 3) * 8192;
    const ushort* al = &sA[sl];
    const ushort* bl = &sB[sl];

    // ------------------ phase A: row-frags 0..3, all cols ------------------
    bf16x8 af0 = *(const bf16x8*)&al[(rbase +  0 + fr) * 32 + fchunk];
    bf16x8 af1 = *(const bf16x8*)&al[(rbase + 16 + fr) * 32 + fchunk];
    bf16x8 af2 = *(const bf16x8*)&al[(rbase + 32 + fr) * 32 + fchunk];
    bf16x8 af3 = *(const bf16x8*)&al[(rbase + 48 + fr) * 32 + fchunk];
    bf16x8 bf0 = *(const bf16x8*)&bl[(cbase +  0 + fr) * 32 + fchunk];
    bf16x8 bf1 = *(const bf16x8*)&bl[(cbase + 16 + fr) * 32 + fchunk];
    bf16x8 bf2 = *(const bf16x8*)&bl[(cbase + 32 + fr) * 32 + fchunk];
    bf16x8 bf3 = *(const bf16x8*)&bl[(cbase + 48 + fr) * 32 + fchunk];
    if (sn < NT) STAGE_A(sn, sln);
    BARRIER();
    __builtin_amdgcn_s_setprio(1);
    MF(0, 0, af0, bf0); MF(1, 0, af1, bf0); MF(2, 0, af2, bf0); MF(3, 0, af3, bf0);
    MF(0, 1, af0, bf1); MF(1, 1, af1, bf1); MF(2, 1, af2, bf1); MF(3, 1, af3, bf1);
    MF(0, 2, af0, bf2); MF(1, 2, af1, bf2); MF(2, 2, af2, bf2); MF(3, 2, af3, bf2);
    MF(0, 3, af0, bf3); MF(1, 3, af1, bf3); MF(2, 3, af2, bf3); MF(3, 3, af3, bf3);
    __builtin_amdgcn_s_setprio(0);
    BARRIER();

    // ------------------ phase B: row-frags 4..7 (B-frags reused) -----------
    af0 = *(const bf16x8*)&al[(rbase +  64 + fr) * 32 + fchunk];
    af1 = *(const bf16x8*)&al[(rbase +  80 + fr) * 32 + fchunk];
    af2 = *(const bf16x8*)&al[(rbase +  96 + fr) * 32 + fchunk];
    af3 = *(const bf16x8*)&al[(rbase + 112 + fr) * 32 + fchunk];
    if (sn < NT) STAGE_B(sn, sln);
    BARRIER();
    __builtin_amdgcn_s_setprio(1);
    MF(4, 0, af0, bf0); MF(5, 0, af1, bf0); MF(6, 0, af2, bf0); MF(7, 0, af3, bf0);
    MF(4, 1, af0, bf1); MF(5, 1, af1, bf1); MF(6, 1, af2, bf1); MF(7, 1, af3, bf1);
    MF(4, 2, af0, bf2); MF(5, 2, af1, bf2); MF(6, 2, af2, bf2); MF(7, 2, af3, bf2);
    MF(4, 3, af0, bf3); MF(5, 3, af1, bf3); MF(6, 3, af2, bf3); MF(7, 3, af3, bf3);
    __builtin_amdgcn_s_setprio(0);
    // group-boundary wait: next step's 8 loads landed; this step's prefetch
    // (4 loads, issued this group) stays in flight across the barrier.
    if (s < NT - 2)       asm volatile("s_waitcnt vmcnt(4)" ::: "memory");
    else if (s == NT - 2) asm volatile("s_waitcnt vmcnt(0)" ::: "memory");
    BARRIER();
  }
#undef MF
#undef STAGE_A
#undef STAGE_B
#undef FENCE
#undef BARRIER

  // ---- epilogue: C = acc + bias (same C/D layout as before) ----
#pragma unroll
  for (int j = 0; j < 4; ++j) {
    const size_t col = brow0 + cbase + j * 16 + fr;
    const float bv = bias[col];
#pragma unroll
    for (int i = 0; i < 8; ++i) {
      const size_t row = arow0 + rbase + i * 16 + fkq * 4;
#pragma unroll
      for (int r = 0; r < 4; ++r)
        C[(row + r) * Ndim + col] = acc[i][j][r] + bv;
    }
  }
}

extern "C" void kernel_launch(void* const* d_in, const int* in_sizes, int n_in,
                              void* d_out, int out_size, void* d_ws, size_t ws_size,
                              hipStream_t stream) {
  const float* x      = (const float*)d_in[0];
  const int*   qw     = (const int*)d_in[1];
  const float* wsc    = (const float*)d_in[2];
  const float* pd     = (const float*)d_in[3];
  const float* pu     = (const float*)d_in[4];
  const float* smooth = (const float*)d_in[5];
  const float* bias   = (const float*)d_in[6];
  float* out = (float*)d_out;

  const size_t abytes = (size_t)Tdim * K2 * 2;          // 34,078,720
  ushort* A    = (ushort*)d_ws;
  ushort* B    = (ushort*)((char*)d_ws + abytes);
  ushort* pdT  = (ushort*)((char*)d_ws + 2 * abytes);   // 32*4096*2 = 256 KB
  float*  part = (float*)((char*)d_ws + 2 * abytes + 262144);  // 16*T*32*4 = 8 MB

  hipLaunchKernelGGL(prep_pdT_kernel, dim3(512),    dim3(256), 0, stream, pd, pdT);
  hipLaunchKernelGGL(prep_a_kernel,   dim3(32, NSPLIT), dim3(256), 0, stream, x, smooth, pdT, A, part);
  hipLaunchKernelGGL(wprep_kernel,    dim3(10240),  dim3(256), 0, stream, qw, wsc, part, pu, A, B);
  hipLaunchKernelGGL(gemm_kernel,     dim3(256),    dim3(512), 0, stream, A, B, bias, out);
}